// Round 1
// baseline (3083.584 us; speedup 1.0000x reference)
//
#include <hip/hip_runtime.h>
#include <stdint.h>

#define N_NODES 50000
#define N_EDGES 800000
#define DIM     128
#define TOT     (N_NODES * DIM)   // 6,400,000

// ---------------- Threefry-2x32 (exact JAX 20-round) ----------------
__host__ __device__ inline void threefry2x32(uint32_t k0, uint32_t k1,
                                             uint32_t x0, uint32_t x1,
                                             uint32_t& o0, uint32_t& o1) {
    uint32_t ks0 = k0, ks1 = k1, ks2 = k0 ^ k1 ^ 0x1BD11BDAu;
    uint32_t v0 = x0 + ks0, v1 = x1 + ks1;
#define TF_R(r) { v0 += v1; v1 = (v1 << (r)) | (v1 >> (32 - (r))); v1 ^= v0; }
    TF_R(13) TF_R(15) TF_R(26) TF_R(6)
    v0 += ks1; v1 += ks2 + 1u;
    TF_R(17) TF_R(29) TF_R(16) TF_R(24)
    v0 += ks2; v1 += ks0 + 2u;
    TF_R(13) TF_R(15) TF_R(26) TF_R(6)
    v0 += ks0; v1 += ks1 + 3u;
    TF_R(17) TF_R(29) TF_R(16) TF_R(24)
    v0 += ks1; v1 += ks2 + 4u;
    TF_R(13) TF_R(15) TF_R(26) TF_R(6)
    v0 += ks2; v1 += ks0 + 5u;
#undef TF_R
    o0 = v0; o1 = v1;
}

// ---------------- degree (A + I), counted at destination ----------------
__global__ void k_degree(const int* __restrict__ dst, uint32_t* __restrict__ deg) {
    int e = blockIdx.x * blockDim.x + threadIdx.x;
    if (e < N_EDGES) atomicAdd(&deg[dst[e]], 1u);
}

__global__ void k_dis(const uint32_t* __restrict__ deg, float* __restrict__ dis) {
    int v = blockIdx.x * blockDim.x + threadIdx.x;
    if (v < N_NODES) dis[v] = 1.0f / sqrtf((float)(deg[v] + 1u));  // +1 self loop
}

// ---------------- H = X @ W  (N x 128 @ 128 x 128), fp32 ----------------
// thread = (row, 4-col group). 1.6M threads.
__global__ void k_gemm128(const float* __restrict__ X, const float* __restrict__ W,
                          float* __restrict__ H) {
    int t = blockIdx.x * blockDim.x + threadIdx.x;
    if (t >= N_NODES * 32) return;
    int row = t >> 5;
    int cg  = t & 31;
    const float4* X4 = (const float4*)X;
    const float4* W4 = (const float4*)W;
    float4 acc = make_float4(0.f, 0.f, 0.f, 0.f);
#pragma unroll 8
    for (int k4 = 0; k4 < 32; ++k4) {
        float4 xv = X4[row * 32 + k4];
        float4 w0 = W4[(k4 * 4 + 0) * 32 + cg];
        float4 w1 = W4[(k4 * 4 + 1) * 32 + cg];
        float4 w2 = W4[(k4 * 4 + 2) * 32 + cg];
        float4 w3 = W4[(k4 * 4 + 3) * 32 + cg];
        acc.x += xv.x * w0.x + xv.y * w1.x + xv.z * w2.x + xv.w * w3.x;
        acc.y += xv.x * w0.y + xv.y * w1.y + xv.z * w2.y + xv.w * w3.y;
        acc.z += xv.x * w0.z + xv.y * w1.z + xv.z * w2.z + xv.w * w3.z;
        acc.w += xv.x * w0.w + xv.y * w1.w + xv.z * w2.w + xv.w * w3.w;
    }
    ((float4*)H)[t] = acc;
}

// ---------------- agg init with self-loop term: agg = h * dis^2 ----------------
__global__ void k_selfinit(const float* __restrict__ H, const float* __restrict__ dis,
                           float* __restrict__ AGG) {
    int t = blockIdx.x * blockDim.x + threadIdx.x;   // over N*32 float4s
    if (t >= N_NODES * 32) return;
    int v = t >> 5;
    float d = dis[v]; float dd = d * d;
    float4 h = ((const float4*)H)[t];
    h.x *= dd; h.y *= dd; h.z *= dd; h.w *= dd;
    ((float4*)AGG)[t] = h;
}

// ---------------- edge scatter-add: agg[dst] += h[src] * norm ----------------
__global__ void k_edge_agg(const int* __restrict__ src, const int* __restrict__ dst,
                           const float* __restrict__ dis, const float* __restrict__ H,
                           float* __restrict__ AGG) {
    long long t = (long long)blockIdx.x * blockDim.x + threadIdx.x; // E*32
    int e = (int)(t >> 5), q = (int)(t & 31);
    if (e >= N_EDGES) return;
    int s = src[e], d = dst[e];
    float nrm = dis[s] * dis[d];
    float4 h = ((const float4*)H)[s * 32 + q];
    float* out = AGG + (size_t)d * DIM + q * 4;
    atomicAdd(out + 0, h.x * nrm);
    atomicAdd(out + 1, h.y * nrm);
    atomicAdd(out + 2, h.z * nrm);
    atomicAdd(out + 3, h.w * nrm);
}

// ---------------- bias + leaky_relu + dropout (threefry partitionable) ----------------
__global__ void k_post(float* __restrict__ buf, const float* __restrict__ bias,
                       uint32_t kk0, uint32_t kk1) {
    int i = blockIdx.x * blockDim.x + threadIdx.x;
    if (i >= TOT) return;
    float z = buf[i] + bias[i & (DIM - 1)];
    z = (z >= 0.f) ? z : 0.01f * z;
    uint32_t b0, b1;
    threefry2x32(kk0, kk1, 0u, (uint32_t)i, b0, b1);
    uint32_t bits = b0 ^ b1;                 // partitionable 32-bit path
    buf[i] = (bits >> 31) ? 0.0f : 2.0f * z; // keep iff u < 0.5 iff top bit 0
}

// ---------------- classifier GEMM: (N x 128) @ (128 x 2) ----------------
__global__ void k_gemm_cls(const float* __restrict__ H, const float* __restrict__ W3,
                           float* __restrict__ O) {
    int v = blockIdx.x * blockDim.x + threadIdx.x;
    if (v >= N_NODES) return;
    const float4* H4 = (const float4*)H;
    float a0 = 0.f, a1 = 0.f;
#pragma unroll 8
    for (int k4 = 0; k4 < 32; ++k4) {
        float4 x = H4[v * 32 + k4];
        const float* w = W3 + k4 * 8;
        a0 += x.x * w[0] + x.y * w[2] + x.z * w[4] + x.w * w[6];
        a1 += x.x * w[1] + x.y * w[3] + x.z * w[5] + x.w * w[7];
    }
    O[v * 2 + 0] = a0;
    O[v * 2 + 1] = a1;
}

__global__ void k_self3(const float* __restrict__ H3, const float* __restrict__ dis,
                        float* __restrict__ AGG3) {
    int i = blockIdx.x * blockDim.x + threadIdx.x;   // N*2
    if (i >= N_NODES * 2) return;
    int v = i >> 1;
    float d = dis[v];
    AGG3[i] = H3[i] * d * d;
}

__global__ void k_edge3(const int* __restrict__ src, const int* __restrict__ dst,
                        const float* __restrict__ dis, const float* __restrict__ H3,
                        float* __restrict__ AGG3) {
    int t = blockIdx.x * blockDim.x + threadIdx.x;   // E*2
    int e = t >> 1, c = t & 1;
    if (e >= N_EDGES) return;
    int s = src[e], d = dst[e];
    atomicAdd(&AGG3[d * 2 + c], H3[s * 2 + c] * dis[s] * dis[d]);
}

__global__ void k_lsm(const float* __restrict__ AGG3, const float* __restrict__ b3,
                      float* __restrict__ out) {
    int v = blockIdx.x * blockDim.x + threadIdx.x;
    if (v >= N_NODES) return;
    float z0 = AGG3[v * 2 + 0] + b3[0];
    float z1 = AGG3[v * 2 + 1] + b3[1];
    float m = fmaxf(z0, z1);
    float lse = m + logf(expf(z0 - m) + expf(z1 - m));
    out[v * 2 + 0] = z0 - lse;
    out[v * 2 + 1] = z1 - lse;
}

extern "C" void kernel_launch(void* const* d_in, const int* in_sizes, int n_in,
                              void* d_out, int out_size, void* d_ws, size_t ws_size,
                              hipStream_t stream) {
    const float* x  = (const float*)d_in[0];
    const int*   ei = (const int*)d_in[1];
    const float* W1 = (const float*)d_in[2];
    const float* b1 = (const float*)d_in[3];
    const float* W2 = (const float*)d_in[4];
    const float* b2 = (const float*)d_in[5];
    const float* W3 = (const float*)d_in[6];
    const float* b3 = (const float*)d_in[7];
    float* out = (float*)d_out;

    const int* src = ei;
    const int* dst = ei + N_EDGES;

    // workspace layout (floats)
    float* ws   = (float*)d_ws;
    uint32_t* deg = (uint32_t*)ws;        // 50000 u32
    float* dis  = ws + 50000;             // 50000
    float* A    = ws + 100000;            // 6.4M  (h buffer; later h3/agg3)
    float* B    = A + TOT;                // 6.4M  (agg buffer / layer input)
    float* h3   = A;                      // reuse A after layer2 (100000)
    float* agg3 = A + 100000;             // reuse A (100000)

    // dropout keys: modern JAX (threefry_partitionable) fold-like split of key(42)
    uint32_t k1a, k1b, k2a, k2b;
    threefry2x32(0u, 42u, 0u, 0u, k1a, k1b);
    threefry2x32(0u, 42u, 0u, 1u, k2a, k2b);

    hipMemsetAsync(deg, 0, N_NODES * sizeof(uint32_t), stream);
    k_degree<<<(N_EDGES + 255) / 256, 256, 0, stream>>>(dst, deg);
    k_dis<<<(N_NODES + 255) / 256, 256, 0, stream>>>(deg, dis);

    // ---- layer 1: x -> A -> B ----
    k_gemm128<<<(N_NODES * 32 + 255) / 256, 256, 0, stream>>>(x, W1, A);
    k_selfinit<<<(N_NODES * 32 + 255) / 256, 256, 0, stream>>>(A, dis, B);
    k_edge_agg<<<(int)(((long long)N_EDGES * 32 + 255) / 256), 256, 0, stream>>>(src, dst, dis, A, B);
    k_post<<<(TOT + 255) / 256, 256, 0, stream>>>(B, b1, k1a, k1b);

    // ---- layer 2: B -> A -> B ----
    k_gemm128<<<(N_NODES * 32 + 255) / 256, 256, 0, stream>>>(B, W2, A);
    // NOTE: selfinit writes all of B before edge atomics; B's old contents consumed by gemm above
    k_selfinit<<<(N_NODES * 32 + 255) / 256, 256, 0, stream>>>(A, dis, B);
    // need a temp: A holds h2, B gets agg2 -- but selfinit already overwrote B using A. OK.
    k_edge_agg<<<(int)(((long long)N_EDGES * 32 + 255) / 256), 256, 0, stream>>>(src, dst, dis, A, B);
    k_post<<<(TOT + 255) / 256, 256, 0, stream>>>(B, b2, k2a, k2b);

    // ---- layer 3: B -> h3 -> agg3 -> out ----
    k_gemm_cls<<<(N_NODES + 255) / 256, 256, 0, stream>>>(B, W3, h3);
    k_self3<<<(N_NODES * 2 + 255) / 256, 256, 0, stream>>>(h3, dis, agg3);
    k_edge3<<<(N_EDGES * 2 + 255) / 256, 256, 0, stream>>>(src, dst, dis, h3, agg3);
    k_lsm<<<(N_NODES + 255) / 256, 256, 0, stream>>>(agg3, b3, out);
}

// Round 2
// 549.993 us; speedup vs baseline: 5.6066x; 5.6066x over previous
//
#include <hip/hip_runtime.h>
#include <stdint.h>

#define N_NODES 50000
#define N_EDGES 800000
#define DIM     128
#define TOT     (N_NODES * DIM)   // 6,400,000
#define SCAN_BLOCKS 196          // 196*256 = 50176 >= 50000

// ---------------- Threefry-2x32 (exact JAX 20-round) ----------------
__host__ __device__ inline void threefry2x32(uint32_t k0, uint32_t k1,
                                             uint32_t x0, uint32_t x1,
                                             uint32_t& o0, uint32_t& o1) {
    uint32_t ks0 = k0, ks1 = k1, ks2 = k0 ^ k1 ^ 0x1BD11BDAu;
    uint32_t v0 = x0 + ks0, v1 = x1 + ks1;
#define TF_R(r) { v0 += v1; v1 = (v1 << (r)) | (v1 >> (32 - (r))); v1 ^= v0; }
    TF_R(13) TF_R(15) TF_R(26) TF_R(6)
    v0 += ks1; v1 += ks2 + 1u;
    TF_R(17) TF_R(29) TF_R(16) TF_R(24)
    v0 += ks2; v1 += ks0 + 2u;
    TF_R(13) TF_R(15) TF_R(26) TF_R(6)
    v0 += ks0; v1 += ks1 + 3u;
    TF_R(17) TF_R(29) TF_R(16) TF_R(24)
    v0 += ks1; v1 += ks2 + 4u;
    TF_R(13) TF_R(15) TF_R(26) TF_R(6)
    v0 += ks2; v1 += ks0 + 5u;
#undef TF_R
    o0 = v0; o1 = v1;
}

__device__ inline float drop_scale(uint32_t kk0, uint32_t kk1, uint32_t i) {
    uint32_t b0, b1;
    threefry2x32(kk0, kk1, 0u, i, b0, b1);
    uint32_t bits = b0 ^ b1;               // partitionable 32-bit path (verified R0)
    return (bits >> 31) ? 0.0f : 2.0f;     // keep iff u < 0.5 iff top bit 0
}

// ---------------- degree (A + I), counted at destination ----------------
__global__ void k_degree(const int* __restrict__ dst, uint32_t* __restrict__ deg) {
    int e = blockIdx.x * blockDim.x + threadIdx.x;
    if (e < N_EDGES) atomicAdd(&deg[dst[e]], 1u);
}

__global__ void k_dis(const uint32_t* __restrict__ deg, float* __restrict__ dis) {
    int v = blockIdx.x * blockDim.x + threadIdx.x;
    if (v < N_NODES) dis[v] = 1.0f / sqrtf((float)(deg[v] + 1u));  // +1 self loop
}

// ---------------- CSR build: prefix sum of deg ----------------
__global__ void k_scan1(const uint32_t* __restrict__ deg, uint32_t* __restrict__ row,
                        uint32_t* __restrict__ bsums) {
    __shared__ uint32_t sm[256];
    int i = blockIdx.x * 256 + threadIdx.x;
    uint32_t v = (i < N_NODES) ? deg[i] : 0u;
    sm[threadIdx.x] = v;
    __syncthreads();
    for (int off = 1; off < 256; off <<= 1) {
        uint32_t t = (threadIdx.x >= off) ? sm[threadIdx.x - off] : 0u;
        __syncthreads();
        sm[threadIdx.x] += t;
        __syncthreads();
    }
    if (i < N_NODES) row[i] = sm[threadIdx.x] - v;   // exclusive within block
    if (threadIdx.x == 255) bsums[blockIdx.x] = sm[255];
}

__global__ void k_scan2(uint32_t* __restrict__ bsums) {
    __shared__ uint32_t sm[256];
    int t = threadIdx.x;
    uint32_t v = (t < SCAN_BLOCKS) ? bsums[t] : 0u;
    sm[t] = v;
    __syncthreads();
    for (int off = 1; off < 256; off <<= 1) {
        uint32_t x = (t >= off) ? sm[t - off] : 0u;
        __syncthreads();
        sm[t] += x;
        __syncthreads();
    }
    if (t < SCAN_BLOCKS) bsums[t] = sm[t] - v;       // exclusive
    if (t == 255) bsums[200 + 56] = sm[255];          // total at slot 256
}

__global__ void k_scan3(uint32_t* __restrict__ row, uint32_t* __restrict__ cursor,
                        const uint32_t* __restrict__ bsums) {
    int i = blockIdx.x * blockDim.x + threadIdx.x;
    if (i < N_NODES) {
        uint32_t r = row[i] + bsums[i >> 8];
        row[i] = r;
        cursor[i] = r;
    } else if (i == N_NODES) {
        row[i] = bsums[256];
    }
}

// ---------------- CSR bucket fill (by destination) ----------------
__global__ void k_bucket(const int* __restrict__ src, const int* __restrict__ dst,
                         const float* __restrict__ dis,
                         uint32_t* __restrict__ cursor,
                         uint32_t* __restrict__ col, float* __restrict__ nrm) {
    int e = blockIdx.x * blockDim.x + threadIdx.x;
    if (e >= N_EDGES) return;
    int s = src[e], d = dst[e];
    uint32_t pos = atomicAdd(&cursor[d], 1u);
    col[pos] = (uint32_t)s;
    nrm[pos] = dis[s] * dis[d];
}

// ---------------- H = X @ W  (N x 128 @ 128 x 128), fp32 ----------------
__global__ void k_gemm128(const float* __restrict__ X, const float* __restrict__ W,
                          float* __restrict__ H) {
    int t = blockIdx.x * blockDim.x + threadIdx.x;
    if (t >= N_NODES * 32) return;
    int row = t >> 5;
    int cg  = t & 31;
    const float4* X4 = (const float4*)X;
    const float4* W4 = (const float4*)W;
    float4 acc = make_float4(0.f, 0.f, 0.f, 0.f);
#pragma unroll 8
    for (int k4 = 0; k4 < 32; ++k4) {
        float4 xv = X4[row * 32 + k4];
        float4 w0 = W4[(k4 * 4 + 0) * 32 + cg];
        float4 w1 = W4[(k4 * 4 + 1) * 32 + cg];
        float4 w2 = W4[(k4 * 4 + 2) * 32 + cg];
        float4 w3 = W4[(k4 * 4 + 3) * 32 + cg];
        acc.x += xv.x * w0.x + xv.y * w1.x + xv.z * w2.x + xv.w * w3.x;
        acc.y += xv.x * w0.y + xv.y * w1.y + xv.z * w2.y + xv.w * w3.y;
        acc.z += xv.x * w0.z + xv.y * w1.z + xv.z * w2.z + xv.w * w3.z;
        acc.w += xv.x * w0.w + xv.y * w1.w + xv.z * w2.w + xv.w * w3.w;
    }
    ((float4*)H)[t] = acc;
}

// ---------------- fused gather + bias + leaky + dropout ----------------
// thread = (node v, 4-col group q). agg = h[v]*dis[v]^2 + sum_e h[col]*nrm
__global__ void k_gather(const uint32_t* __restrict__ row, const uint32_t* __restrict__ col,
                         const float* __restrict__ nrm, const float* __restrict__ dis,
                         const float* __restrict__ H, const float* __restrict__ bias,
                         float* __restrict__ OUT, uint32_t kk0, uint32_t kk1) {
    int t = blockIdx.x * blockDim.x + threadIdx.x;
    if (t >= N_NODES * 32) return;
    int v = t >> 5;
    int q = t & 31;
    const float4* H4 = (const float4*)H;
    float d = dis[v];
    float4 acc = H4[v * 32 + q];
    float dd = d * d;
    acc.x *= dd; acc.y *= dd; acc.z *= dd; acc.w *= dd;
    uint32_t e0 = row[v], e1 = row[v + 1];
    for (uint32_t e = e0; e < e1; ++e) {
        uint32_t s = col[e];
        float w = nrm[e];
        float4 h = H4[s * 32 + q];
        acc.x += h.x * w; acc.y += h.y * w; acc.z += h.z * w; acc.w += h.w * w;
    }
    // epilogue: bias + leaky_relu + dropout
    float* ap = (float*)&acc;
    int cbase = q * 4;
    uint32_t ibase = (uint32_t)(v * DIM + cbase);
#pragma unroll
    for (int j = 0; j < 4; ++j) {
        float z = ap[j] + bias[cbase + j];
        z = (z >= 0.f) ? z : 0.01f * z;
        ap[j] = z * drop_scale(kk0, kk1, ibase + j);
    }
    ((float4*)OUT)[t] = acc;
}

// ---------------- classifier GEMM: (N x 128) @ (128 x 2) ----------------
__global__ void k_gemm_cls(const float* __restrict__ H, const float* __restrict__ W3,
                           float* __restrict__ O) {
    int v = blockIdx.x * blockDim.x + threadIdx.x;
    if (v >= N_NODES) return;
    const float4* H4 = (const float4*)H;
    float a0 = 0.f, a1 = 0.f;
#pragma unroll 8
    for (int k4 = 0; k4 < 32; ++k4) {
        float4 x = H4[v * 32 + k4];
        const float* w = W3 + k4 * 8;
        a0 += x.x * w[0] + x.y * w[2] + x.z * w[4] + x.w * w[6];
        a1 += x.x * w[1] + x.y * w[3] + x.z * w[5] + x.w * w[7];
    }
    O[v * 2 + 0] = a0;
    O[v * 2 + 1] = a1;
}

// ---------------- fused layer-3 gather + bias + log_softmax ----------------
__global__ void k_gather3(const uint32_t* __restrict__ row, const uint32_t* __restrict__ col,
                          const float* __restrict__ nrm, const float* __restrict__ dis,
                          const float* __restrict__ H3, const float* __restrict__ b3,
                          float* __restrict__ out) {
    int v = blockIdx.x * blockDim.x + threadIdx.x;
    if (v >= N_NODES) return;
    const float2* H2 = (const float2*)H3;
    float d = dis[v]; float dd = d * d;
    float2 h = H2[v];
    float z0 = h.x * dd, z1 = h.y * dd;
    uint32_t e0 = row[v], e1 = row[v + 1];
    for (uint32_t e = e0; e < e1; ++e) {
        uint32_t s = col[e];
        float w = nrm[e];
        float2 hs = H2[s];
        z0 += hs.x * w; z1 += hs.y * w;
    }
    z0 += b3[0]; z1 += b3[1];
    float m = fmaxf(z0, z1);
    float lse = m + logf(expf(z0 - m) + expf(z1 - m));
    out[v * 2 + 0] = z0 - lse;
    out[v * 2 + 1] = z1 - lse;
}

extern "C" void kernel_launch(void* const* d_in, const int* in_sizes, int n_in,
                              void* d_out, int out_size, void* d_ws, size_t ws_size,
                              hipStream_t stream) {
    const float* x  = (const float*)d_in[0];
    const int*   ei = (const int*)d_in[1];
    const float* W1 = (const float*)d_in[2];
    const float* b1 = (const float*)d_in[3];
    const float* W2 = (const float*)d_in[4];
    const float* b2 = (const float*)d_in[5];
    const float* W3 = (const float*)d_in[6];
    const float* b3 = (const float*)d_in[7];
    float* out = (float*)d_out;

    const int* src = ei;
    const int* dst = ei + N_EDGES;

    // workspace layout (4-byte units)
    uint32_t* wsu = (uint32_t*)d_ws;
    float*    wsf = (float*)d_ws;
    uint32_t* deg    = wsu;                // [0, 50000)
    float*    dis    = wsf + 50000;        // [50000, 100000)
    uint32_t* row    = wsu + 100000;       // [100000, 150001)
    uint32_t* cursor = wsu + 150016;       // [150016, 200016)
    uint32_t* bsums  = wsu + 200016;       // [200016, 200273)  (total at +256)
    uint32_t* col    = wsu + 200288;       // [200288, 1000288)
    float*    nrm    = wsf + 1000288;      // [1000288, 1800288)
    float*    A      = wsf + 1800288;      // 6.4M
    float*    B      = A + TOT;            // 6.4M
    float*    h3     = A;                  // reuse A after layer 2 (100000 floats)

    // dropout keys: threefry-partitionable fold-like split of key(42) (verified R0)
    uint32_t k1a, k1b, k2a, k2b;
    threefry2x32(0u, 42u, 0u, 0u, k1a, k1b);
    threefry2x32(0u, 42u, 0u, 1u, k2a, k2b);

    // ---- graph preprocessing: degree, dis, CSR ----
    hipMemsetAsync(deg, 0, N_NODES * sizeof(uint32_t), stream);
    k_degree<<<(N_EDGES + 255) / 256, 256, 0, stream>>>(dst, deg);
    k_dis<<<(N_NODES + 255) / 256, 256, 0, stream>>>(deg, dis);
    k_scan1<<<SCAN_BLOCKS, 256, 0, stream>>>(deg, row, bsums);
    k_scan2<<<1, 256, 0, stream>>>(bsums);
    k_scan3<<<(N_NODES + 256) / 256, 256, 0, stream>>>(row, cursor, bsums);
    k_bucket<<<(N_EDGES + 255) / 256, 256, 0, stream>>>(src, dst, dis, cursor, col, nrm);

    // ---- layer 1: x -> A(h) -> B(agg+act+drop) ----
    k_gemm128<<<(N_NODES * 32 + 255) / 256, 256, 0, stream>>>(x, W1, A);
    k_gather<<<(N_NODES * 32 + 255) / 256, 256, 0, stream>>>(row, col, nrm, dis, A, b1, B, k1a, k1b);

    // ---- layer 2: B -> A(h) -> B(agg+act+drop) ----
    k_gemm128<<<(N_NODES * 32 + 255) / 256, 256, 0, stream>>>(B, W2, A);
    k_gather<<<(N_NODES * 32 + 255) / 256, 256, 0, stream>>>(row, col, nrm, dis, A, b2, B, k2a, k2b);

    // ---- layer 3: B -> h3 -> out ----
    k_gemm_cls<<<(N_NODES + 255) / 256, 256, 0, stream>>>(B, W3, h3);
    k_gather3<<<(N_NODES + 255) / 256, 256, 0, stream>>>(row, col, nrm, dis, h3, b3, out);
}

// Round 3
// 395.992 us; speedup vs baseline: 7.7870x; 1.3889x over previous
//
#include <hip/hip_runtime.h>
#include <stdint.h>

#define N_NODES 50000
#define N_EDGES 800000
#define DIM     128
#define TOT     (N_NODES * DIM)   // 6,400,000
#define SCAN_BLOCKS 196          // 196*256 = 50176 >= 50000
#define BM 64
#define BK 32

// ---------------- Threefry-2x32 (exact JAX 20-round) ----------------
__host__ __device__ inline void threefry2x32(uint32_t k0, uint32_t k1,
                                             uint32_t x0, uint32_t x1,
                                             uint32_t& o0, uint32_t& o1) {
    uint32_t ks0 = k0, ks1 = k1, ks2 = k0 ^ k1 ^ 0x1BD11BDAu;
    uint32_t v0 = x0 + ks0, v1 = x1 + ks1;
#define TF_R(r) { v0 += v1; v1 = (v1 << (r)) | (v1 >> (32 - (r))); v1 ^= v0; }
    TF_R(13) TF_R(15) TF_R(26) TF_R(6)
    v0 += ks1; v1 += ks2 + 1u;
    TF_R(17) TF_R(29) TF_R(16) TF_R(24)
    v0 += ks2; v1 += ks0 + 2u;
    TF_R(13) TF_R(15) TF_R(26) TF_R(6)
    v0 += ks0; v1 += ks1 + 3u;
    TF_R(17) TF_R(29) TF_R(16) TF_R(24)
    v0 += ks1; v1 += ks2 + 4u;
    TF_R(13) TF_R(15) TF_R(26) TF_R(6)
    v0 += ks2; v1 += ks0 + 5u;
#undef TF_R
    o0 = v0; o1 = v1;
}

__device__ inline float drop_scale(uint32_t kk0, uint32_t kk1, uint32_t i) {
    uint32_t b0, b1;
    threefry2x32(kk0, kk1, 0u, i, b0, b1);
    uint32_t bits = b0 ^ b1;               // partitionable 32-bit path (verified R0)
    return (bits >> 31) ? 0.0f : 2.0f;     // keep iff u < 0.5 iff top bit 0
}

// ---------------- degree (A + I), counted at destination ----------------
__global__ void k_degree(const int* __restrict__ dst, uint32_t* __restrict__ deg) {
    int e = blockIdx.x * blockDim.x + threadIdx.x;
    if (e < N_EDGES) atomicAdd(&deg[dst[e]], 1u);
}

__global__ void k_dis(const uint32_t* __restrict__ deg, float* __restrict__ dis) {
    int v = blockIdx.x * blockDim.x + threadIdx.x;
    if (v < N_NODES) dis[v] = 1.0f / sqrtf((float)(deg[v] + 1u));  // +1 self loop
}

// ---------------- CSR build: prefix sum of deg ----------------
__global__ void k_scan1(const uint32_t* __restrict__ deg, uint32_t* __restrict__ row,
                        uint32_t* __restrict__ bsums) {
    __shared__ uint32_t sm[256];
    int i = blockIdx.x * 256 + threadIdx.x;
    uint32_t v = (i < N_NODES) ? deg[i] : 0u;
    sm[threadIdx.x] = v;
    __syncthreads();
    for (int off = 1; off < 256; off <<= 1) {
        uint32_t t = (threadIdx.x >= off) ? sm[threadIdx.x - off] : 0u;
        __syncthreads();
        sm[threadIdx.x] += t;
        __syncthreads();
    }
    if (i < N_NODES) row[i] = sm[threadIdx.x] - v;   // exclusive within block
    if (threadIdx.x == 255) bsums[blockIdx.x] = sm[255];
}

__global__ void k_scan2(uint32_t* __restrict__ bsums) {
    __shared__ uint32_t sm[256];
    int t = threadIdx.x;
    uint32_t v = (t < SCAN_BLOCKS) ? bsums[t] : 0u;
    sm[t] = v;
    __syncthreads();
    for (int off = 1; off < 256; off <<= 1) {
        uint32_t x = (t >= off) ? sm[t - off] : 0u;
        __syncthreads();
        sm[t] += x;
        __syncthreads();
    }
    if (t < SCAN_BLOCKS) bsums[t] = sm[t] - v;       // exclusive
    if (t == 255) bsums[256] = sm[255];               // total at slot 256
}

__global__ void k_scan3(uint32_t* __restrict__ row, uint32_t* __restrict__ cursor,
                        const uint32_t* __restrict__ bsums) {
    int i = blockIdx.x * blockDim.x + threadIdx.x;
    if (i < N_NODES) {
        uint32_t r = row[i] + bsums[i >> 8];
        row[i] = r;
        cursor[i] = r;
    } else if (i == N_NODES) {
        row[i] = bsums[256];
    }
}

// ---------------- CSR bucket fill (by destination) ----------------
__global__ void k_bucket(const int* __restrict__ src, const int* __restrict__ dst,
                         const float* __restrict__ dis,
                         uint32_t* __restrict__ cursor,
                         uint32_t* __restrict__ col, float* __restrict__ nrm) {
    int e = blockIdx.x * blockDim.x + threadIdx.x;
    if (e >= N_EDGES) return;
    int s = src[e], d = dst[e];
    uint32_t pos = atomicAdd(&cursor[d], 1u);
    col[pos] = (uint32_t)s;
    nrm[pos] = dis[s] * dis[d];
}

// ---------------- H = X @ W  (N x 128 @ 128 x 128), fp32, LDS-tiled ----------------
// Block: 64 rows x 128 cols. Thread: 8 rows x 4 cols register tile.
// LDS: Xs (k-major, 8KB) + Ws (16KB) = 24KB.
__global__ __launch_bounds__(256) void k_gemm128(const float* __restrict__ X,
                                                 const float* __restrict__ W,
                                                 float* __restrict__ H) {
    __shared__ float Xs[BK][BM];    // [k][row], transposed on store
    __shared__ float Ws[BK][DIM];   // [k][col]
    int tid = threadIdx.x;
    int m0 = blockIdx.x * BM;
    int cg = tid & 31;              // col group: cols cg*4 .. cg*4+3
    int rg = tid >> 5;              // row group: rows rg*8 .. rg*8+7 (in tile)
    float acc[8][4] = {};
    const float4* X4 = (const float4*)X;
    const float4* W4 = (const float4*)W;

    for (int kt = 0; kt < DIM; kt += BK) {
        // stage X tile: 64 rows x 32 k = 512 float4s, 2 per thread, transpose into Xs
        #pragma unroll
        for (int i = 0; i < 2; ++i) {
            int r  = (tid >> 3) + i * 32;        // 0..63
            int kc = tid & 7;                    // float4 chunk within BK
            int grow = m0 + r;
            int gr = (grow < N_NODES) ? grow : 0;
            float4 xv = X4[gr * 32 + (kt >> 2) + kc];
            Xs[kc * 4 + 0][r] = xv.x;            // per-inst: lanes hit distinct rows -> distinct banks
            Xs[kc * 4 + 1][r] = xv.y;
            Xs[kc * 4 + 2][r] = xv.z;
            Xs[kc * 4 + 3][r] = xv.w;
        }
        // stage W slab: 32 k x 128 cols = 1024 float4s, 4 per thread, direct copy
        #pragma unroll
        for (int i = 0; i < 4; ++i) {
            int idx = tid + i * 256;             // 0..1023
            int k   = idx >> 5;
            int c4  = idx & 31;
            float4 wv = W4[(kt + k) * 32 + c4];
            *((float4*)&Ws[k][c4 * 4]) = wv;
        }
        __syncthreads();

        #pragma unroll 8
        for (int k = 0; k < BK; ++k) {
            float4 wv = *((const float4*)&Ws[k][cg * 4]);
            float4 xa = *((const float4*)&Xs[k][rg * 8]);
            float4 xb = *((const float4*)&Xs[k][rg * 8 + 4]);
            float xr[8] = {xa.x, xa.y, xa.z, xa.w, xb.x, xb.y, xb.z, xb.w};
            #pragma unroll
            for (int r = 0; r < 8; ++r) {
                acc[r][0] += xr[r] * wv.x;
                acc[r][1] += xr[r] * wv.y;
                acc[r][2] += xr[r] * wv.z;
                acc[r][3] += xr[r] * wv.w;
            }
        }
        __syncthreads();
    }

    #pragma unroll
    for (int r = 0; r < 8; ++r) {
        int grow = m0 + rg * 8 + r;
        if (grow < N_NODES) {
            float4 o = make_float4(acc[r][0], acc[r][1], acc[r][2], acc[r][3]);
            ((float4*)H)[grow * 32 + cg] = o;
        }
    }
}

// ---------------- fused gather + bias + leaky + dropout ----------------
// thread = (node v, 4-col group q). agg = h[v]*dis[v]^2 + sum_e h[col]*nrm
__global__ void k_gather(const uint32_t* __restrict__ row, const uint32_t* __restrict__ col,
                         const float* __restrict__ nrm, const float* __restrict__ dis,
                         const float* __restrict__ H, const float* __restrict__ bias,
                         float* __restrict__ OUT, uint32_t kk0, uint32_t kk1) {
    int t = blockIdx.x * blockDim.x + threadIdx.x;
    if (t >= N_NODES * 32) return;
    int v = t >> 5;
    int q = t & 31;
    const float4* H4 = (const float4*)H;
    float d = dis[v];
    float4 acc = H4[v * 32 + q];
    float dd = d * d;
    acc.x *= dd; acc.y *= dd; acc.z *= dd; acc.w *= dd;
    uint32_t e0 = row[v], e1 = row[v + 1];
    for (uint32_t e = e0; e < e1; ++e) {
        uint32_t s = col[e];
        float w = nrm[e];
        float4 h = H4[s * 32 + q];
        acc.x += h.x * w; acc.y += h.y * w; acc.z += h.z * w; acc.w += h.w * w;
    }
    float* ap = (float*)&acc;
    int cbase = q * 4;
    uint32_t ibase = (uint32_t)(v * DIM + cbase);
#pragma unroll
    for (int j = 0; j < 4; ++j) {
        float z = ap[j] + bias[cbase + j];
        z = (z >= 0.f) ? z : 0.01f * z;
        ap[j] = z * drop_scale(kk0, kk1, ibase + j);
    }
    ((float4*)OUT)[t] = acc;
}

// ---------------- classifier GEMM: (N x 128) @ (128 x 2) ----------------
__global__ void k_gemm_cls(const float* __restrict__ H, const float* __restrict__ W3,
                           float* __restrict__ O) {
    int v = blockIdx.x * blockDim.x + threadIdx.x;
    if (v >= N_NODES) return;
    const float4* H4 = (const float4*)H;
    float a0 = 0.f, a1 = 0.f;
#pragma unroll 8
    for (int k4 = 0; k4 < 32; ++k4) {
        float4 x = H4[v * 32 + k4];
        const float* w = W3 + k4 * 8;
        a0 += x.x * w[0] + x.y * w[2] + x.z * w[4] + x.w * w[6];
        a1 += x.x * w[1] + x.y * w[3] + x.z * w[5] + x.w * w[7];
    }
    O[v * 2 + 0] = a0;
    O[v * 2 + 1] = a1;
}

// ---------------- fused layer-3 gather + bias + log_softmax ----------------
__global__ void k_gather3(const uint32_t* __restrict__ row, const uint32_t* __restrict__ col,
                          const float* __restrict__ nrm, const float* __restrict__ dis,
                          const float* __restrict__ H3, const float* __restrict__ b3,
                          float* __restrict__ out) {
    int v = blockIdx.x * blockDim.x + threadIdx.x;
    if (v >= N_NODES) return;
    const float2* H2 = (const float2*)H3;
    float d = dis[v]; float dd = d * d;
    float2 h = H2[v];
    float z0 = h.x * dd, z1 = h.y * dd;
    uint32_t e0 = row[v], e1 = row[v + 1];
    for (uint32_t e = e0; e < e1; ++e) {
        uint32_t s = col[e];
        float w = nrm[e];
        float2 hs = H2[s];
        z0 += hs.x * w; z1 += hs.y * w;
    }
    z0 += b3[0]; z1 += b3[1];
    float m = fmaxf(z0, z1);
    float lse = m + logf(expf(z0 - m) + expf(z1 - m));
    out[v * 2 + 0] = z0 - lse;
    out[v * 2 + 1] = z1 - lse;
}

extern "C" void kernel_launch(void* const* d_in, const int* in_sizes, int n_in,
                              void* d_out, int out_size, void* d_ws, size_t ws_size,
                              hipStream_t stream) {
    const float* x  = (const float*)d_in[0];
    const int*   ei = (const int*)d_in[1];
    const float* W1 = (const float*)d_in[2];
    const float* b1 = (const float*)d_in[3];
    const float* W2 = (const float*)d_in[4];
    const float* b2 = (const float*)d_in[5];
    const float* W3 = (const float*)d_in[6];
    const float* b3 = (const float*)d_in[7];
    float* out = (float*)d_out;

    const int* src = ei;
    const int* dst = ei + N_EDGES;

    // workspace layout (4-byte units)
    uint32_t* wsu = (uint32_t*)d_ws;
    float*    wsf = (float*)d_ws;
    uint32_t* deg    = wsu;                // [0, 50000)
    float*    dis    = wsf + 50000;        // [50000, 100000)
    uint32_t* row    = wsu + 100000;       // [100000, 150001)
    uint32_t* cursor = wsu + 150016;       // [150016, 200016)
    uint32_t* bsums  = wsu + 200016;       // [200016, 200273)  (total at +256)
    uint32_t* col    = wsu + 200288;       // [200288, 1000288)
    float*    nrm    = wsf + 1000288;      // [1000288, 1800288)
    float*    A      = wsf + 1800288;      // 6.4M
    float*    B      = A + TOT;            // 6.4M
    float*    h3     = A;                  // reuse A after layer 2 (100000 floats)

    // dropout keys: threefry-partitionable fold-like split of key(42) (verified R0)
    uint32_t k1a, k1b, k2a, k2b;
    threefry2x32(0u, 42u, 0u, 0u, k1a, k1b);
    threefry2x32(0u, 42u, 0u, 1u, k2a, k2b);

    // ---- graph preprocessing: degree, dis, CSR ----
    hipMemsetAsync(deg, 0, N_NODES * sizeof(uint32_t), stream);
    k_degree<<<(N_EDGES + 255) / 256, 256, 0, stream>>>(dst, deg);
    k_dis<<<(N_NODES + 255) / 256, 256, 0, stream>>>(deg, dis);
    k_scan1<<<SCAN_BLOCKS, 256, 0, stream>>>(deg, row, bsums);
    k_scan2<<<1, 256, 0, stream>>>(bsums);
    k_scan3<<<(N_NODES + 256) / 256, 256, 0, stream>>>(row, cursor, bsums);
    k_bucket<<<(N_EDGES + 255) / 256, 256, 0, stream>>>(src, dst, dis, cursor, col, nrm);

    // ---- layer 1: x -> A(h) -> B(agg+act+drop) ----
    k_gemm128<<<(N_NODES + BM - 1) / BM, 256, 0, stream>>>(x, W1, A);
    k_gather<<<(N_NODES * 32 + 255) / 256, 256, 0, stream>>>(row, col, nrm, dis, A, b1, B, k1a, k1b);

    // ---- layer 2: B -> A(h) -> B(agg+act+drop) ----
    k_gemm128<<<(N_NODES + BM - 1) / BM, 256, 0, stream>>>(B, W2, A);
    k_gather<<<(N_NODES * 32 + 255) / 256, 256, 0, stream>>>(row, col, nrm, dis, A, b2, B, k2a, k2b);

    // ---- layer 3: B -> h3 -> out ----
    k_gemm_cls<<<(N_NODES + 255) / 256, 256, 0, stream>>>(B, W3, h3);
    k_gather3<<<(N_NODES + 255) / 256, 256, 0, stream>>>(row, col, nrm, dis, h3, b3, out);
}

// Round 4
// 380.681 us; speedup vs baseline: 8.1002x; 1.0402x over previous
//
#include <hip/hip_runtime.h>
#include <stdint.h>

#define N_NODES 50000
#define N_EDGES 800000
#define DIM     128
#define TOT     (N_NODES * DIM)   // 6,400,000
#define SCAN_BLOCKS 196          // 196*256 = 50176 >= 50000
#define GBM 128                  // GEMM block rows
#define BK  32                   // GEMM k-tile

// ---------------- Threefry-2x32 (exact JAX 20-round) ----------------
__host__ __device__ inline void threefry2x32(uint32_t k0, uint32_t k1,
                                             uint32_t x0, uint32_t x1,
                                             uint32_t& o0, uint32_t& o1) {
    uint32_t ks0 = k0, ks1 = k1, ks2 = k0 ^ k1 ^ 0x1BD11BDAu;
    uint32_t v0 = x0 + ks0, v1 = x1 + ks1;
#define TF_R(r) { v0 += v1; v1 = (v1 << (r)) | (v1 >> (32 - (r))); v1 ^= v0; }
    TF_R(13) TF_R(15) TF_R(26) TF_R(6)
    v0 += ks1; v1 += ks2 + 1u;
    TF_R(17) TF_R(29) TF_R(16) TF_R(24)
    v0 += ks2; v1 += ks0 + 2u;
    TF_R(13) TF_R(15) TF_R(26) TF_R(6)
    v0 += ks0; v1 += ks1 + 3u;
    TF_R(17) TF_R(29) TF_R(16) TF_R(24)
    v0 += ks1; v1 += ks2 + 4u;
    TF_R(13) TF_R(15) TF_R(26) TF_R(6)
    v0 += ks2; v1 += ks0 + 5u;
#undef TF_R
    o0 = v0; o1 = v1;
}

__device__ inline float drop_scale(uint32_t kk0, uint32_t kk1, uint32_t i) {
    uint32_t b0, b1;
    threefry2x32(kk0, kk1, 0u, i, b0, b1);
    uint32_t bits = b0 ^ b1;               // partitionable 32-bit path (verified R0)
    return (bits >> 31) ? 0.0f : 2.0f;     // keep iff u < 0.5 iff top bit 0
}

__device__ inline float bf2f(ushort u) {
    return __uint_as_float(((uint32_t)u) << 16);
}

__device__ inline ushort f2bf_rne(float f) {
    uint32_t bits = __float_as_uint(f);
    uint32_t lsb = (bits >> 16) & 1u;
    bits += 0x7fffu + lsb;                 // round-to-nearest-even
    return (ushort)(bits >> 16);
}

// ---------------- degree (A + I), counted at destination ----------------
__global__ void k_degree(const int* __restrict__ dst, uint32_t* __restrict__ deg) {
    int e = blockIdx.x * blockDim.x + threadIdx.x;
    if (e < N_EDGES) atomicAdd(&deg[dst[e]], 1u);
}

__global__ void k_dis(const uint32_t* __restrict__ deg, float* __restrict__ dis) {
    int v = blockIdx.x * blockDim.x + threadIdx.x;
    if (v < N_NODES) dis[v] = 1.0f / sqrtf((float)(deg[v] + 1u));  // +1 self loop
}

// ---------------- CSR build: prefix sum of deg ----------------
__global__ void k_scan1(const uint32_t* __restrict__ deg, uint32_t* __restrict__ row,
                        uint32_t* __restrict__ bsums) {
    __shared__ uint32_t sm[256];
    int i = blockIdx.x * 256 + threadIdx.x;
    uint32_t v = (i < N_NODES) ? deg[i] : 0u;
    sm[threadIdx.x] = v;
    __syncthreads();
    for (int off = 1; off < 256; off <<= 1) {
        uint32_t t = (threadIdx.x >= off) ? sm[threadIdx.x - off] : 0u;
        __syncthreads();
        sm[threadIdx.x] += t;
        __syncthreads();
    }
    if (i < N_NODES) row[i] = sm[threadIdx.x] - v;   // exclusive within block
    if (threadIdx.x == 255) bsums[blockIdx.x] = sm[255];
}

__global__ void k_scan2(uint32_t* __restrict__ bsums) {
    __shared__ uint32_t sm[256];
    int t = threadIdx.x;
    uint32_t v = (t < SCAN_BLOCKS) ? bsums[t] : 0u;
    sm[t] = v;
    __syncthreads();
    for (int off = 1; off < 256; off <<= 1) {
        uint32_t x = (t >= off) ? sm[t - off] : 0u;
        __syncthreads();
        sm[t] += x;
        __syncthreads();
    }
    if (t < SCAN_BLOCKS) bsums[t] = sm[t] - v;       // exclusive
    if (t == 255) bsums[256] = sm[255];               // total at slot 256
}

__global__ void k_scan3(uint32_t* __restrict__ row, uint32_t* __restrict__ cursor,
                        const uint32_t* __restrict__ bsums) {
    int i = blockIdx.x * blockDim.x + threadIdx.x;
    if (i < N_NODES) {
        uint32_t r = row[i] + bsums[i >> 8];
        row[i] = r;
        cursor[i] = r;
    } else if (i == N_NODES) {
        row[i] = bsums[256];
    }
}

// ---------------- CSR bucket fill (by destination) ----------------
__global__ void k_bucket(const int* __restrict__ src, const int* __restrict__ dst,
                         const float* __restrict__ dis,
                         uint32_t* __restrict__ cursor,
                         uint32_t* __restrict__ col, float* __restrict__ nrm) {
    int e = blockIdx.x * blockDim.x + threadIdx.x;
    if (e >= N_EDGES) return;
    int s = src[e], d = dst[e];
    uint32_t pos = atomicAdd(&cursor[d], 1u);
    col[pos] = (uint32_t)s;
    nrm[pos] = dis[s] * dis[d];
}

// ---------------- H = X @ W, fp32 compute, bf16 output ----------------
// Block: 128 rows x 128 cols, thread: 8x8 register tile.
// LDS: Xs [k][row] 16KB + Ws [k][col] 16KB = 32KB.
__global__ __launch_bounds__(256) void k_gemm128(const float* __restrict__ X,
                                                 const float* __restrict__ W,
                                                 ushort* __restrict__ Hb) {
    __shared__ float Xs[BK][GBM];
    __shared__ float Ws[BK][DIM];
    int tid = threadIdx.x;
    int m0 = blockIdx.x * GBM;
    int cg = tid & 15;              // cols cg*8 .. cg*8+7
    int rg = tid >> 4;              // rows rg*8 .. rg*8+7 (in tile)
    float acc[8][8] = {};
    const float4* X4 = (const float4*)X;
    const float4* W4 = (const float4*)W;

    for (int kt = 0; kt < DIM; kt += BK) {
        // stage X tile: 128 rows x 32 k = 1024 float4s, 4/thread, transpose
        #pragma unroll
        for (int i = 0; i < 4; ++i) {
            int idx = tid + i * 256;             // 0..1023
            int r   = idx >> 3;                  // 0..127
            int kc  = idx & 7;                   // float4 chunk in BK
            int grow = m0 + r;
            int gr = (grow < N_NODES) ? grow : 0;
            float4 xv = X4[gr * 32 + (kt >> 2) + kc];
            Xs[kc * 4 + 0][r] = xv.x;
            Xs[kc * 4 + 1][r] = xv.y;
            Xs[kc * 4 + 2][r] = xv.z;
            Xs[kc * 4 + 3][r] = xv.w;
        }
        // stage W slab: 32 k x 128 cols = 1024 float4s, 4/thread
        #pragma unroll
        for (int i = 0; i < 4; ++i) {
            int idx = tid + i * 256;
            int k   = idx >> 5;
            int c4  = idx & 31;
            *((float4*)&Ws[k][c4 * 4]) = W4[(kt + k) * 32 + c4];
        }
        __syncthreads();

        #pragma unroll 4
        for (int k = 0; k < BK; ++k) {
            float4 xa = *((const float4*)&Xs[k][rg * 8]);
            float4 xb = *((const float4*)&Xs[k][rg * 8 + 4]);
            float4 wa = *((const float4*)&Ws[k][cg * 8]);
            float4 wb = *((const float4*)&Ws[k][cg * 8 + 4]);
            float xr[8] = {xa.x, xa.y, xa.z, xa.w, xb.x, xb.y, xb.z, xb.w};
            float wc[8] = {wa.x, wa.y, wa.z, wa.w, wb.x, wb.y, wb.z, wb.w};
            #pragma unroll
            for (int r = 0; r < 8; ++r)
                #pragma unroll
                for (int c = 0; c < 8; ++c)
                    acc[r][c] += xr[r] * wc[c];
        }
        __syncthreads();
    }

    #pragma unroll
    for (int r = 0; r < 8; ++r) {
        int grow = m0 + rg * 8 + r;
        if (grow < N_NODES) {
            ushort4 s0, s1;
            s0.x = f2bf_rne(acc[r][0]); s0.y = f2bf_rne(acc[r][1]);
            s0.z = f2bf_rne(acc[r][2]); s0.w = f2bf_rne(acc[r][3]);
            s1.x = f2bf_rne(acc[r][4]); s1.y = f2bf_rne(acc[r][5]);
            s1.z = f2bf_rne(acc[r][6]); s1.w = f2bf_rne(acc[r][7]);
            ((ushort4*)Hb)[grow * 32 + cg * 2 + 0] = s0;
            ((ushort4*)Hb)[grow * 32 + cg * 2 + 1] = s1;
        }
    }
}

// ---------------- fused gather (bf16 table) + bias + leaky + dropout ----------------
// thread = (node v, 4-feature group q). agg = h[v]*dis^2 + sum_e h[col]*nrm
__global__ void k_gather(const uint32_t* __restrict__ row, const uint32_t* __restrict__ col,
                         const float* __restrict__ nrm, const float* __restrict__ dis,
                         const ushort* __restrict__ Hb, const float* __restrict__ bias,
                         float* __restrict__ OUT, uint32_t kk0, uint32_t kk1) {
    int t = blockIdx.x * blockDim.x + threadIdx.x;
    if (t >= N_NODES * 32) return;
    int v = t >> 5;
    int q = t & 31;
    const ushort4* H4 = (const ushort4*)Hb;   // 32 ushort4 per node row
    float d = dis[v];
    float dd = d * d;
    ushort4 hv = H4[v * 32 + q];
    float4 acc;
    acc.x = bf2f(hv.x) * dd; acc.y = bf2f(hv.y) * dd;
    acc.z = bf2f(hv.z) * dd; acc.w = bf2f(hv.w) * dd;
    uint32_t e0 = row[v], e1 = row[v + 1];
    for (uint32_t e = e0; e < e1; ++e) {
        uint32_t s = col[e];
        float w = nrm[e];
        ushort4 hs = H4[s * 32 + q];
        acc.x += bf2f(hs.x) * w; acc.y += bf2f(hs.y) * w;
        acc.z += bf2f(hs.z) * w; acc.w += bf2f(hs.w) * w;
    }
    float* ap = (float*)&acc;
    int cbase = q * 4;
    uint32_t ibase = (uint32_t)(v * DIM + cbase);
#pragma unroll
    for (int j = 0; j < 4; ++j) {
        float z = ap[j] + bias[cbase + j];
        z = (z >= 0.f) ? z : 0.01f * z;
        ap[j] = z * drop_scale(kk0, kk1, ibase + j);
    }
    ((float4*)OUT)[t] = acc;
}

// ---------------- classifier GEMM: (N x 128) @ (128 x 2) ----------------
__global__ void k_gemm_cls(const float* __restrict__ H, const float* __restrict__ W3,
                           float* __restrict__ O) {
    int v = blockIdx.x * blockDim.x + threadIdx.x;
    if (v >= N_NODES) return;
    const float4* H4 = (const float4*)H;
    float a0 = 0.f, a1 = 0.f;
#pragma unroll 8
    for (int k4 = 0; k4 < 32; ++k4) {
        float4 x = H4[v * 32 + k4];
        const float* w = W3 + k4 * 8;
        a0 += x.x * w[0] + x.y * w[2] + x.z * w[4] + x.w * w[6];
        a1 += x.x * w[1] + x.y * w[3] + x.z * w[5] + x.w * w[7];
    }
    O[v * 2 + 0] = a0;
    O[v * 2 + 1] = a1;
}

// ---------------- fused layer-3 gather + bias + log_softmax ----------------
__global__ void k_gather3(const uint32_t* __restrict__ row, const uint32_t* __restrict__ col,
                          const float* __restrict__ nrm, const float* __restrict__ dis,
                          const float* __restrict__ H3, const float* __restrict__ b3,
                          float* __restrict__ out) {
    int v = blockIdx.x * blockDim.x + threadIdx.x;
    if (v >= N_NODES) return;
    const float2* H2 = (const float2*)H3;
    float d = dis[v]; float dd = d * d;
    float2 h = H2[v];
    float z0 = h.x * dd, z1 = h.y * dd;
    uint32_t e0 = row[v], e1 = row[v + 1];
    for (uint32_t e = e0; e < e1; ++e) {
        uint32_t s = col[e];
        float w = nrm[e];
        float2 hs = H2[s];
        z0 += hs.x * w; z1 += hs.y * w;
    }
    z0 += b3[0]; z1 += b3[1];
    float m = fmaxf(z0, z1);
    float lse = m + logf(expf(z0 - m) + expf(z1 - m));
    out[v * 2 + 0] = z0 - lse;
    out[v * 2 + 1] = z1 - lse;
}

extern "C" void kernel_launch(void* const* d_in, const int* in_sizes, int n_in,
                              void* d_out, int out_size, void* d_ws, size_t ws_size,
                              hipStream_t stream) {
    const float* x  = (const float*)d_in[0];
    const int*   ei = (const int*)d_in[1];
    const float* W1 = (const float*)d_in[2];
    const float* b1 = (const float*)d_in[3];
    const float* W2 = (const float*)d_in[4];
    const float* b2 = (const float*)d_in[5];
    const float* W3 = (const float*)d_in[6];
    const float* b3 = (const float*)d_in[7];
    float* out = (float*)d_out;

    const int* src = ei;
    const int* dst = ei + N_EDGES;

    // workspace layout (4-byte units)
    uint32_t* wsu = (uint32_t*)d_ws;
    float*    wsf = (float*)d_ws;
    uint32_t* deg    = wsu;                // [0, 50000)
    float*    dis    = wsf + 50000;        // [50000, 100000)
    uint32_t* row    = wsu + 100000;       // [100000, 150001)
    uint32_t* cursor = wsu + 150016;       // [150016, 200016)
    uint32_t* bsums  = wsu + 200016;       // [200016, 200273) (total at +256)
    uint32_t* col    = wsu + 200288;       // [200288, 1000288)
    float*    nrm    = wsf + 1000288;      // [1000288, 1800288)
    ushort*   Hb     = (ushort*)(wsf + 1800288);  // bf16 H table: 6.4M ushorts (3.2M floats)
    float*    B      = wsf + 1800288 + 3200000;   // fp32 activations, 6.4M floats
    float*    h3     = wsf + 1800288;      // reuse Hb region after layer 2 (100000 floats)

    // dropout keys: threefry-partitionable fold-like split of key(42) (verified R0)
    uint32_t k1a, k1b, k2a, k2b;
    threefry2x32(0u, 42u, 0u, 0u, k1a, k1b);
    threefry2x32(0u, 42u, 0u, 1u, k2a, k2b);

    // ---- graph preprocessing: degree, dis, CSR ----
    hipMemsetAsync(deg, 0, N_NODES * sizeof(uint32_t), stream);
    k_degree<<<(N_EDGES + 255) / 256, 256, 0, stream>>>(dst, deg);
    k_dis<<<(N_NODES + 255) / 256, 256, 0, stream>>>(deg, dis);
    k_scan1<<<SCAN_BLOCKS, 256, 0, stream>>>(deg, row, bsums);
    k_scan2<<<1, 256, 0, stream>>>(bsums);
    k_scan3<<<(N_NODES + 256) / 256, 256, 0, stream>>>(row, cursor, bsums);
    k_bucket<<<(N_EDGES + 255) / 256, 256, 0, stream>>>(src, dst, dis, cursor, col, nrm);

    // ---- layer 1: x -> Hb(bf16) -> B(fp32) ----
    k_gemm128<<<(N_NODES + GBM - 1) / GBM, 256, 0, stream>>>(x, W1, Hb);
    k_gather<<<(N_NODES * 32 + 255) / 256, 256, 0, stream>>>(row, col, nrm, dis, Hb, b1, B, k1a, k1b);

    // ---- layer 2: B -> Hb(bf16) -> B(fp32) ----
    k_gemm128<<<(N_NODES + GBM - 1) / GBM, 256, 0, stream>>>(B, W2, Hb);
    k_gather<<<(N_NODES * 32 + 255) / 256, 256, 0, stream>>>(row, col, nrm, dis, Hb, b2, B, k2a, k2b);

    // ---- layer 3: B -> h3 -> out ----
    k_gemm_cls<<<(N_NODES + 255) / 256, 256, 0, stream>>>(B, W3, h3);
    k_gather3<<<(N_NODES + 255) / 256, 256, 0, stream>>>(row, col, nrm, dis, h3, b3, out);
}

// Round 5
// 346.288 us; speedup vs baseline: 8.9047x; 1.0993x over previous
//
#include <hip/hip_runtime.h>
#include <stdint.h>

#define N_NODES 50000
#define N_EDGES 800000
#define DIM     128
#define TOT     (N_NODES * DIM)   // 6,400,000
#define SCAN_BLOCKS 196          // 196*256 = 50176 >= 50000
#define GBM 128                  // GEMM block rows
#define BK  32                   // GEMM k-tile

// ---------------- Threefry-2x32 (exact JAX 20-round) ----------------
__host__ __device__ inline void threefry2x32(uint32_t k0, uint32_t k1,
                                             uint32_t x0, uint32_t x1,
                                             uint32_t& o0, uint32_t& o1) {
    uint32_t ks0 = k0, ks1 = k1, ks2 = k0 ^ k1 ^ 0x1BD11BDAu;
    uint32_t v0 = x0 + ks0, v1 = x1 + ks1;
#define TF_R(r) { v0 += v1; v1 = (v1 << (r)) | (v1 >> (32 - (r))); v1 ^= v0; }
    TF_R(13) TF_R(15) TF_R(26) TF_R(6)
    v0 += ks1; v1 += ks2 + 1u;
    TF_R(17) TF_R(29) TF_R(16) TF_R(24)
    v0 += ks2; v1 += ks0 + 2u;
    TF_R(13) TF_R(15) TF_R(26) TF_R(6)
    v0 += ks0; v1 += ks1 + 3u;
    TF_R(17) TF_R(29) TF_R(16) TF_R(24)
    v0 += ks1; v1 += ks2 + 4u;
    TF_R(13) TF_R(15) TF_R(26) TF_R(6)
    v0 += ks2; v1 += ks0 + 5u;
#undef TF_R
    o0 = v0; o1 = v1;
}

__device__ inline float drop_scale(uint32_t kk0, uint32_t kk1, uint32_t i) {
    uint32_t b0, b1;
    threefry2x32(kk0, kk1, 0u, i, b0, b1);
    uint32_t bits = b0 ^ b1;               // partitionable 32-bit path (verified R0)
    return (bits >> 31) ? 0.0f : 2.0f;     // keep iff u < 0.5 iff top bit 0
}

__device__ inline float bf2f(ushort u) {
    return __uint_as_float(((uint32_t)u) << 16);
}

__device__ inline ushort f2bf_rne(float f) {
    uint32_t bits = __float_as_uint(f);
    uint32_t lsb = (bits >> 16) & 1u;
    bits += 0x7fffu + lsb;                 // round-to-nearest-even
    return (ushort)(bits >> 16);
}

// ---------------- degree (A + I), counted at destination ----------------
__global__ void k_degree(const int* __restrict__ dst, uint32_t* __restrict__ deg) {
    int e = blockIdx.x * blockDim.x + threadIdx.x;
    if (e < N_EDGES) atomicAdd(&deg[dst[e]], 1u);
}

__global__ void k_dis(const uint32_t* __restrict__ deg, float* __restrict__ dis) {
    int v = blockIdx.x * blockDim.x + threadIdx.x;
    if (v < N_NODES) dis[v] = 1.0f / sqrtf((float)(deg[v] + 1u));  // +1 self loop
}

// ---------------- CSR build: prefix sum of deg ----------------
__global__ void k_scan1(const uint32_t* __restrict__ deg, uint32_t* __restrict__ row,
                        uint32_t* __restrict__ bsums) {
    __shared__ uint32_t sm[256];
    int i = blockIdx.x * 256 + threadIdx.x;
    uint32_t v = (i < N_NODES) ? deg[i] : 0u;
    sm[threadIdx.x] = v;
    __syncthreads();
    for (int off = 1; off < 256; off <<= 1) {
        uint32_t t = (threadIdx.x >= off) ? sm[threadIdx.x - off] : 0u;
        __syncthreads();
        sm[threadIdx.x] += t;
        __syncthreads();
    }
    if (i < N_NODES) row[i] = sm[threadIdx.x] - v;   // exclusive within block
    if (threadIdx.x == 255) bsums[blockIdx.x] = sm[255];
}

__global__ void k_scan2(uint32_t* __restrict__ bsums) {
    __shared__ uint32_t sm[256];
    int t = threadIdx.x;
    uint32_t v = (t < SCAN_BLOCKS) ? bsums[t] : 0u;
    sm[t] = v;
    __syncthreads();
    for (int off = 1; off < 256; off <<= 1) {
        uint32_t x = (t >= off) ? sm[t - off] : 0u;
        __syncthreads();
        sm[t] += x;
        __syncthreads();
    }
    if (t < SCAN_BLOCKS) bsums[t] = sm[t] - v;       // exclusive
    if (t == 255) bsums[256] = sm[255];               // total at slot 256
}

__global__ void k_scan3(uint32_t* __restrict__ row, uint32_t* __restrict__ cursor,
                        const uint32_t* __restrict__ bsums) {
    int i = blockIdx.x * blockDim.x + threadIdx.x;
    if (i < N_NODES) {
        uint32_t r = row[i] + bsums[i >> 8];
        row[i] = r;
        cursor[i] = r;
    } else if (i == N_NODES) {
        row[i] = bsums[256];
    }
}

// ---------------- CSR bucket fill (by destination), col only ----------------
__global__ void k_bucket(const int* __restrict__ src, const int* __restrict__ dst,
                         uint32_t* __restrict__ cursor,
                         uint32_t* __restrict__ col) {
    int e = blockIdx.x * blockDim.x + threadIdx.x;
    if (e >= N_EDGES) return;
    int s = src[e], d = dst[e];
    uint32_t pos = atomicAdd(&cursor[d], 1u);
    col[pos] = (uint32_t)s;
}

// ---------------- H = X @ W, fp32 compute, bf16 scaled output ----------------
// Writes Hs[v] = (X@W)[v] * dis[v] in bf16.
// Block: 128 rows x 128 cols, thread: 8x8 register tile. LDS 32KB.
__global__ __launch_bounds__(256) void k_gemm128(const float* __restrict__ X,
                                                 const float* __restrict__ W,
                                                 const float* __restrict__ dis,
                                                 ushort* __restrict__ Hb) {
    __shared__ float Xs[BK][GBM];
    __shared__ float Ws[BK][DIM];
    int tid = threadIdx.x;
    int m0 = blockIdx.x * GBM;
    int cg = tid & 15;              // cols cg*8 .. cg*8+7
    int rg = tid >> 4;              // rows rg*8 .. rg*8+7 (in tile)
    float acc[8][8] = {};
    const float4* X4 = (const float4*)X;
    const float4* W4 = (const float4*)W;

    for (int kt = 0; kt < DIM; kt += BK) {
        #pragma unroll
        for (int i = 0; i < 4; ++i) {
            int idx = tid + i * 256;             // 0..1023
            int r   = idx >> 3;                  // 0..127
            int kc  = idx & 7;                   // float4 chunk in BK
            int grow = m0 + r;
            int gr = (grow < N_NODES) ? grow : 0;
            float4 xv = X4[gr * 32 + (kt >> 2) + kc];
            Xs[kc * 4 + 0][r] = xv.x;
            Xs[kc * 4 + 1][r] = xv.y;
            Xs[kc * 4 + 2][r] = xv.z;
            Xs[kc * 4 + 3][r] = xv.w;
        }
        #pragma unroll
        for (int i = 0; i < 4; ++i) {
            int idx = tid + i * 256;
            int k   = idx >> 5;
            int c4  = idx & 31;
            *((float4*)&Ws[k][c4 * 4]) = W4[(kt + k) * 32 + c4];
        }
        __syncthreads();

        #pragma unroll 4
        for (int k = 0; k < BK; ++k) {
            float4 xa = *((const float4*)&Xs[k][rg * 8]);
            float4 xb = *((const float4*)&Xs[k][rg * 8 + 4]);
            float4 wa = *((const float4*)&Ws[k][cg * 8]);
            float4 wb = *((const float4*)&Ws[k][cg * 8 + 4]);
            float xr[8] = {xa.x, xa.y, xa.z, xa.w, xb.x, xb.y, xb.z, xb.w};
            float wc[8] = {wa.x, wa.y, wa.z, wa.w, wb.x, wb.y, wb.z, wb.w};
            #pragma unroll
            for (int r = 0; r < 8; ++r)
                #pragma unroll
                for (int c = 0; c < 8; ++c)
                    acc[r][c] += xr[r] * wc[c];
        }
        __syncthreads();
    }

    #pragma unroll
    for (int r = 0; r < 8; ++r) {
        int grow = m0 + rg * 8 + r;
        if (grow < N_NODES) {
            float dv = dis[grow];
            ushort4 s0, s1;
            s0.x = f2bf_rne(acc[r][0] * dv); s0.y = f2bf_rne(acc[r][1] * dv);
            s0.z = f2bf_rne(acc[r][2] * dv); s0.w = f2bf_rne(acc[r][3] * dv);
            s1.x = f2bf_rne(acc[r][4] * dv); s1.y = f2bf_rne(acc[r][5] * dv);
            s1.z = f2bf_rne(acc[r][6] * dv); s1.w = f2bf_rne(acc[r][7] * dv);
            ((ushort4*)Hb)[grow * 32 + cg * 2 + 0] = s0;
            ((ushort4*)Hb)[grow * 32 + cg * 2 + 1] = s1;
        }
    }
}

// ---------------- fused gather (scaled bf16 table) + bias + leaky + dropout ----
// agg[v] = dis[v] * (Hs[v] + sum_e Hs[col[e]]);  then bias/leaky/dropout.
__global__ void k_gather(const uint32_t* __restrict__ row, const uint32_t* __restrict__ col,
                         const float* __restrict__ dis,
                         const ushort* __restrict__ Hb, const float* __restrict__ bias,
                         float* __restrict__ OUT, uint32_t kk0, uint32_t kk1) {
    int t = blockIdx.x * blockDim.x + threadIdx.x;
    if (t >= N_NODES * 32) return;
    int v = t >> 5;
    int q = t & 31;
    const ushort4* H4 = (const ushort4*)Hb;   // 32 ushort4 per node row
    ushort4 hv = H4[v * 32 + q];
    float4 acc;
    acc.x = bf2f(hv.x); acc.y = bf2f(hv.y);
    acc.z = bf2f(hv.z); acc.w = bf2f(hv.w);
    uint32_t e0 = row[v], e1 = row[v + 1];
    uint32_t e = e0;
    // 2-way unrolled: two independent row gathers in flight
    for (; e + 2 <= e1; e += 2) {
        uint32_t s0 = col[e], s1 = col[e + 1];
        ushort4 h0 = H4[s0 * 32 + q];
        ushort4 h1 = H4[s1 * 32 + q];
        acc.x += bf2f(h0.x) + bf2f(h1.x);
        acc.y += bf2f(h0.y) + bf2f(h1.y);
        acc.z += bf2f(h0.z) + bf2f(h1.z);
        acc.w += bf2f(h0.w) + bf2f(h1.w);
    }
    if (e < e1) {
        uint32_t s0 = col[e];
        ushort4 h0 = H4[s0 * 32 + q];
        acc.x += bf2f(h0.x); acc.y += bf2f(h0.y);
        acc.z += bf2f(h0.z); acc.w += bf2f(h0.w);
    }
    float dv = dis[v];
    float* ap = (float*)&acc;
    int cbase = q * 4;
    uint32_t ibase = (uint32_t)(v * DIM + cbase);
#pragma unroll
    for (int j = 0; j < 4; ++j) {
        float z = ap[j] * dv + bias[cbase + j];
        z = (z >= 0.f) ? z : 0.01f * z;
        ap[j] = z * drop_scale(kk0, kk1, ibase + j);
    }
    ((float4*)OUT)[t] = acc;
}

// ---------------- classifier GEMM: (N x 128) @ (128 x 2), scaled output ------
__global__ void k_gemm_cls(const float* __restrict__ H, const float* __restrict__ W3,
                           const float* __restrict__ dis, float* __restrict__ O) {
    int v = blockIdx.x * blockDim.x + threadIdx.x;
    if (v >= N_NODES) return;
    const float4* H4 = (const float4*)H;
    float a0 = 0.f, a1 = 0.f;
#pragma unroll 8
    for (int k4 = 0; k4 < 32; ++k4) {
        float4 x = H4[v * 32 + k4];
        const float* w = W3 + k4 * 8;
        a0 += x.x * w[0] + x.y * w[2] + x.z * w[4] + x.w * w[6];
        a1 += x.x * w[1] + x.y * w[3] + x.z * w[5] + x.w * w[7];
    }
    float dv = dis[v];
    O[v * 2 + 0] = a0 * dv;
    O[v * 2 + 1] = a1 * dv;
}

// ---------------- fused layer-3 gather + bias + log_softmax ----------------
// z[v] = dis[v] * (h3s[v] + sum_e h3s[col[e]]) + b3
__global__ void k_gather3(const uint32_t* __restrict__ row, const uint32_t* __restrict__ col,
                          const float* __restrict__ dis,
                          const float* __restrict__ H3s, const float* __restrict__ b3,
                          float* __restrict__ out) {
    int v = blockIdx.x * blockDim.x + threadIdx.x;
    if (v >= N_NODES) return;
    const float2* H2 = (const float2*)H3s;
    float2 h = H2[v];
    float z0 = h.x, z1 = h.y;
    uint32_t e0 = row[v], e1 = row[v + 1];
    uint32_t e = e0;
    for (; e + 2 <= e1; e += 2) {
        float2 ha = H2[col[e]];
        float2 hb = H2[col[e + 1]];
        z0 += ha.x + hb.x; z1 += ha.y + hb.y;
    }
    if (e < e1) {
        float2 ha = H2[col[e]];
        z0 += ha.x; z1 += ha.y;
    }
    float dv = dis[v];
    z0 = z0 * dv + b3[0];
    z1 = z1 * dv + b3[1];
    float m = fmaxf(z0, z1);
    float lse = m + logf(expf(z0 - m) + expf(z1 - m));
    out[v * 2 + 0] = z0 - lse;
    out[v * 2 + 1] = z1 - lse;
}

extern "C" void kernel_launch(void* const* d_in, const int* in_sizes, int n_in,
                              void* d_out, int out_size, void* d_ws, size_t ws_size,
                              hipStream_t stream) {
    const float* x  = (const float*)d_in[0];
    const int*   ei = (const int*)d_in[1];
    const float* W1 = (const float*)d_in[2];
    const float* b1 = (const float*)d_in[3];
    const float* W2 = (const float*)d_in[4];
    const float* b2 = (const float*)d_in[5];
    const float* W3 = (const float*)d_in[6];
    const float* b3 = (const float*)d_in[7];
    float* out = (float*)d_out;

    const int* src = ei;
    const int* dst = ei + N_EDGES;

    // workspace layout (4-byte units)
    uint32_t* wsu = (uint32_t*)d_ws;
    float*    wsf = (float*)d_ws;
    uint32_t* deg    = wsu;                       // [0, 50000)
    float*    dis    = wsf + 50000;               // [50000, 100000)
    uint32_t* row    = wsu + 100000;              // [100000, 150001)
    uint32_t* cursor = wsu + 150016;              // [150016, 200016)
    uint32_t* bsums  = wsu + 200016;              // [200016, 200273) (total at +256)
    uint32_t* col    = wsu + 200288;              // [200288, 1000288)
    ushort*   Hb     = (ushort*)(wsf + 1000288);  // bf16 scaled H: 6.4M ushorts
    float*    B      = wsf + 1000288 + 3200000;   // fp32 activations, 6.4M floats
    float*    h3s    = wsf + 1000288;             // reuse Hb region (100000 floats)

    // dropout keys: threefry-partitionable fold-like split of key(42) (verified R0)
    uint32_t k1a, k1b, k2a, k2b;
    threefry2x32(0u, 42u, 0u, 0u, k1a, k1b);
    threefry2x32(0u, 42u, 0u, 1u, k2a, k2b);

    // ---- graph preprocessing: degree, dis, CSR ----
    hipMemsetAsync(deg, 0, N_NODES * sizeof(uint32_t), stream);
    k_degree<<<(N_EDGES + 255) / 256, 256, 0, stream>>>(dst, deg);
    k_dis<<<(N_NODES + 255) / 256, 256, 0, stream>>>(deg, dis);
    k_scan1<<<SCAN_BLOCKS, 256, 0, stream>>>(deg, row, bsums);
    k_scan2<<<1, 256, 0, stream>>>(bsums);
    k_scan3<<<(N_NODES + 256) / 256, 256, 0, stream>>>(row, cursor, bsums);
    k_bucket<<<(N_EDGES + 255) / 256, 256, 0, stream>>>(src, dst, cursor, col);

    // ---- layer 1: x -> Hb(bf16, pre-scaled) -> B(fp32) ----
    k_gemm128<<<(N_NODES + GBM - 1) / GBM, 256, 0, stream>>>(x, W1, dis, Hb);
    k_gather<<<(N_NODES * 32 + 255) / 256, 256, 0, stream>>>(row, col, dis, Hb, b1, B, k1a, k1b);

    // ---- layer 2: B -> Hb(bf16, pre-scaled) -> B(fp32) ----
    k_gemm128<<<(N_NODES + GBM - 1) / GBM, 256, 0, stream>>>(B, W2, dis, Hb);
    k_gather<<<(N_NODES * 32 + 255) / 256, 256, 0, stream>>>(row, col, dis, Hb, b2, B, k2a, k2b);

    // ---- layer 3: B -> h3s(pre-scaled) -> out ----
    k_gemm_cls<<<(N_NODES + 255) / 256, 256, 0, stream>>>(B, W3, dis, h3s);
    k_gather3<<<(N_NODES + 255) / 256, 256, 0, stream>>>(row, col, dis, h3s, b3, out);
}